// Round 1
// baseline (236.050 us; speedup 1.0000x reference)
//
#include <hip/hip_runtime.h>
#include <hip/hip_bf16.h>

typedef __attribute__((ext_vector_type(8))) short short8;
typedef __attribute__((ext_vector_type(4))) float f32x4;

__device__ __forceinline__ unsigned short f2bf(float f) {
    unsigned u = __float_as_uint(f);
    u += 0x7fffu + ((u >> 16) & 1u);   // RNE to bf16
    return (unsigned short)(u >> 16);
}
__device__ __forceinline__ float bf2f(unsigned u16) {
    return __uint_as_float(u16 << 16);
}
__device__ __forceinline__ unsigned pk2(float a, float b) {
    return (unsigned)f2bf(a) | ((unsigned)f2bf(b) << 16);
}
// multiply two packed bf16x2 words elementwise, return packed bf16x2
__device__ __forceinline__ unsigned mulpack(unsigned a, unsigned b) {
    float alo = bf2f(a & 0xffffu), ahi = bf2f(a >> 16);
    float blo = bf2f(b & 0xffffu), bhi = bf2f(b >> 16);
    return pk2(alo * blo, ahi * bhi);
}

// v1b = bf16(z_out + z_self), v2b = bf16(z_in + z_self)
__global__ __launch_bounds__(256) void prep_kernel(
    const float4* __restrict__ zin, const float4* __restrict__ zout,
    const float4* __restrict__ zself,
    ushort4* __restrict__ v1b, ushort4* __restrict__ v2b, int n4)
{
    int i = blockIdx.x * 256 + threadIdx.x;
    if (i >= n4) return;
    float4 o = zout[i], s = zself[i], z = zin[i];
    ushort4 a, b;
    a.x = f2bf(o.x + s.x); a.y = f2bf(o.y + s.y);
    a.z = f2bf(o.z + s.z); a.w = f2bf(o.w + s.w);
    b.x = f2bf(z.x + s.x); b.y = f2bf(z.y + s.y);
    b.z = f2bf(z.z + s.z); b.w = f2bf(z.w + s.w);
    v1b[i] = a; v2b[i] = b;
}

// One wave per 16-edge tile: gather -> bf16 value tile in LDS -> 16x MFMA
// (16x16x32 bf16, K=128, 64 outputs) -> +b1, ELU, dot W2, +b2, sigmoid.
template <bool FUSED>
__global__ __launch_bounds__(256) void edge_kernel(
    const unsigned short* __restrict__ v1b, const unsigned short* __restrict__ v2b,
    const float* __restrict__ zin, const float* __restrict__ zout,
    const float* __restrict__ zself,
    const int* __restrict__ idx,
    const float* __restrict__ W1, const float* __restrict__ b1,
    const float* __restrict__ W2, const float* __restrict__ b2,
    float* __restrict__ out, int E, int ntiles)
{
    // per-wave value tile: 16 edges x 128 bf16, row stride 136 (272B) vs 128
    // to break the all-rows-hit-bank-0 aliasing of a 256B stride.
    __shared__ __align__(16) unsigned short lds_val[4][16][136];

    const int wave = threadIdx.x >> 6;
    const int lane = threadIdx.x & 63;
    const int nn = lane & 15;   // A-row (edge) on reads; B/D column
    const int q  = lane >> 4;   // quad

    // W1 fragments, register-resident for the whole kernel.
    // B[k][n] with n = lane&15 -> j = jt*16+nn, k = kc*32 + q*8 + t
    short8 Bf[4][4];
#pragma unroll
    for (int kc = 0; kc < 4; kc++)
#pragma unroll
        for (int jt = 0; jt < 4; jt++) {
            short8 v;
#pragma unroll
            for (int t = 0; t < 8; t++)
                v[t] = (short)f2bf(W1[(kc * 32 + q * 8 + t) * 64 + jt * 16 + nn]);
            Bf[kc][jt] = v;
        }
    float bias1[4], w2v[4];
#pragma unroll
    for (int jt = 0; jt < 4; jt++) {
        bias1[jt] = b1[jt * 16 + nn];
        w2v[jt]   = W2[jt * 16 + nn];
    }
    const float b2v = b2[0];

    const int ge   = lane >> 2;        // gather: edge within tile (0..15)
    const int cblk = (lane & 3) * 32;  // gather: channel block base

    const int nwaves = gridDim.x * 4;
    for (int tile = blockIdx.x * 4 + wave; tile < ntiles; tile += nwaves) {
        const int ebase = tile * 16;
        const int ee  = min(ebase + ge, E - 1);
        const int src = idx[ee];
        const int dst = idx[E + ee];

        uint4 prod[4];  // 32 bf16 products for this lane's 32 channels
        if (FUSED) {
            const uint4* p1 = (const uint4*)(v1b + (size_t)src * 128 + cblk);
            const uint4* p2 = (const uint4*)(v2b + (size_t)dst * 128 + cblk);
#pragma unroll
            for (int i = 0; i < 4; i++) {
                uint4 a = p1[i], c = p2[i];
                prod[i].x = mulpack(a.x, c.x);
                prod[i].y = mulpack(a.y, c.y);
                prod[i].z = mulpack(a.z, c.z);
                prod[i].w = mulpack(a.w, c.w);
            }
        } else {
            const float* po  = zout  + (size_t)src * 128 + cblk;
            const float* ps1 = zself + (size_t)src * 128 + cblk;
            const float* pi  = zin   + (size_t)dst * 128 + cblk;
            const float* ps2 = zself + (size_t)dst * 128 + cblk;
#pragma unroll
            for (int i = 0; i < 4; i++) {
                float4 oa = *(const float4*)(po  + i * 8), ob = *(const float4*)(po  + i * 8 + 4);
                float4 sa = *(const float4*)(ps1 + i * 8), sb = *(const float4*)(ps1 + i * 8 + 4);
                float4 ia = *(const float4*)(pi  + i * 8), ib = *(const float4*)(pi  + i * 8 + 4);
                float4 ta = *(const float4*)(ps2 + i * 8), tb = *(const float4*)(ps2 + i * 8 + 4);
                prod[i].x = pk2((oa.x + sa.x) * (ia.x + ta.x), (oa.y + sa.y) * (ia.y + ta.y));
                prod[i].y = pk2((oa.z + sa.z) * (ia.z + ta.z), (oa.w + sa.w) * (ia.w + ta.w));
                prod[i].z = pk2((ob.x + sb.x) * (ib.x + tb.x), (ob.y + sb.y) * (ib.y + tb.y));
                prod[i].w = pk2((ob.z + sb.z) * (ib.z + tb.z), (ob.w + sb.w) * (ib.w + tb.w));
            }
        }

#pragma unroll
        for (int i = 0; i < 4; i++)
            *(uint4*)&lds_val[wave][ge][cblk + i * 8] = prod[i];

        // wave-internal RAW on our own LDS region: drain lgkm, keep vmcnt free.
        __builtin_amdgcn_sched_barrier(0);
        __builtin_amdgcn_s_waitcnt(0xC07F);   // vmcnt(63) expcnt(7) lgkmcnt(0)
        __builtin_amdgcn_sched_barrier(0);

        short8 Af[4];
#pragma unroll
        for (int kc = 0; kc < 4; kc++)
            Af[kc] = *(const short8*)&lds_val[wave][nn][kc * 32 + q * 8];

        f32x4 acc[4];
#pragma unroll
        for (int jt = 0; jt < 4; jt++) acc[jt] = (f32x4){0.f, 0.f, 0.f, 0.f};
#pragma unroll
        for (int kc = 0; kc < 4; kc++)
#pragma unroll
            for (int jt = 0; jt < 4; jt++)
                acc[jt] = __builtin_amdgcn_mfma_f32_16x16x32_bf16(
                    Af[kc], Bf[kc][jt], acc[jt], 0, 0, 0);

        // epilogue: h = ELU(acc + b1); partial = sum_j h*W2[j] over this lane's n
        float ps[4];
#pragma unroll
        for (int r = 0; r < 4; r++) {
            float s = 0.f;
#pragma unroll
            for (int jt = 0; jt < 4; jt++) {
                float h = acc[jt][r] + bias1[jt];
                h = (h > 0.f) ? h : (__expf(h) - 1.f);
                s += h * w2v[jt];
            }
            ps[r] = s;
        }
        // reduce across the 16 lanes of this quad (n = 0..15)
#pragma unroll
        for (int off = 1; off < 16; off <<= 1) {
#pragma unroll
            for (int r = 0; r < 4; r++)
                ps[r] += __shfl_xor(ps[r], off, 64);
        }
        if (nn == 0) {
#pragma unroll
            for (int r = 0; r < 4; r++) {
                int e = ebase + q * 4 + r;   // D row = quad*4 + reg
                if (e < E) {
                    float x = ps[r] + b2v;
                    out[e] = 1.f / (1.f + __expf(-x));
                }
            }
        }
    }
}

extern "C" void kernel_launch(void* const* d_in, const int* in_sizes, int n_in,
                              void* d_out, int out_size, void* d_ws, size_t ws_size,
                              hipStream_t stream)
{
    const float* zin   = (const float*)d_in[0];
    const float* zout  = (const float*)d_in[1];
    const float* zself = (const float*)d_in[2];
    const int*   idx   = (const int*)d_in[3];
    const float* W1    = (const float*)d_in[4];
    const float* b1    = (const float*)d_in[5];
    const float* W2    = (const float*)d_in[6];
    const float* b2    = (const float*)d_in[7];
    float* out = (float*)d_out;

    const int NC = in_sizes[0];          // N*C
    const int E  = in_sizes[3] / 2;
    const int ntiles = (E + 15) / 16;
    const size_t need = (size_t)NC * 4;  // two bf16 [N,C] arrays

    if (ws_size >= need) {
        unsigned short* v1b = (unsigned short*)d_ws;
        unsigned short* v2b = v1b + NC;
        const int n4 = NC / 4;
        prep_kernel<<<(n4 + 255) / 256, 256, 0, stream>>>(
            (const float4*)zin, (const float4*)zout, (const float4*)zself,
            (ushort4*)v1b, (ushort4*)v2b, n4);
        edge_kernel<true><<<2048, 256, 0, stream>>>(
            v1b, v2b, zin, zout, zself, idx, W1, b1, W2, b2, out, E, ntiles);
    } else {
        edge_kernel<false><<<2048, 256, 0, stream>>>(
            nullptr, nullptr, zin, zout, zself, idx, W1, b1, W2, b2, out, E, ntiles);
    }
}